// Round 13
// baseline (123.412 us; speedup 1.0000x reference)
//
#include <hip/hip_runtime.h>

// OPU via MFMA, R13 = R11 with main's body repeated x3 (MEASUREMENT ROUND).
// Rationale: opu_main (~25us) has been invisible below the harness's 43us ws-poison
// fills since R5; four structural theories (barrier drain, prefetch depth, register-feed
// traffic, TLP/occupancy) produced mutually contradictory neutral results; issue-cycle
// arithmetic says ~5us vs measured ~25us. One sacrificial round makes main a ~75us
// dispatch so rocprof finally reports MfmaUtil/VALUBusy/Occupancy/FETCH for it.
// rep_stride (runtime 0) is added to every plane base so the compiler cannot prove
// passes identical and elide them. Out is stored identically each pass (idempotent).
// Everything else identical to R11 (best known: 91.1us total).
//   presplit: a = fl(x + vlut[k%16][x+8]); b = fl(w + wlut[k%16][w+8])*(1/16) (exact);
//   f16 hi/lo split; planes XH/XL[mblk32][chunk64][rg2][oct2][row32][k8],
//   WH/WL[nblk16][chunk64][ng2][oct2][n32][k8] u16. LDS-transposed coalesced X stores.
//   main: 512 blocks (2/CU) x 256 thr; block = 64x64 tile; wave = 16-chunk k-slice;
//   literal double-buffer (R7 scratch lesson), 12 MFMA/chunk (AhBh+AlBh+AhBl, AlBl
//   dropped), res += rndne(acc) (clip provably dead), 4-barrier LDS combine, x16 store.

typedef unsigned int u32;
typedef unsigned short u16;
typedef _Float16 f16x8 __attribute__((ext_vector_type(8)));
typedef float f32x16 __attribute__((ext_vector_type(16)));

#define M_TOT 2048
#define N_TOT 1024
#define K_TOT 1024

__global__ __launch_bounds__(256) void presplit(
    const float* __restrict__ x, const float* __restrict__ w,
    const float* __restrict__ vl, const float* __restrict__ wl,
    u16* __restrict__ XH, u16* __restrict__ XL,
    u16* __restrict__ WH, u16* __restrict__ WL)
{
  __shared__ __align__(16) char lds[16384];   // [H 8KB | L 8KB], 4 chunk-planes each
  const int b = blockIdx.x;
  const int tid = threadIdx.x;

  if (b < 512) {
    // X: block = (mblk, chunk-group of 4). thread = (m_local, ch_local).
    const int mblk = b >> 4, chg = b & 15;
    const int ml = tid >> 2, chl = tid & 3;
    const int rg = ml >> 5, row = ml & 31;
    const int m = mblk * 64 + ml;
    const float* xp = x + (size_t)m * K_TOT + (chg * 4 + chl) * 16;

    u32 hp[8], lp[8];
#pragma unroll
    for (int e2 = 0; e2 < 8; ++e2) {
      u16 h2[2], l2[2];
#pragma unroll
      for (int q = 0; q < 2; ++q) {
        const int e = e2 * 2 + q;
        const float v = xp[e];
        const int xi = (int)(v + 8.0f);          // x always in [-8,7]
        const float a = v + vl[e * 16 + xi];     // j = k%16 = e (chunk-aligned)
        const _Float16 h = (_Float16)a;
        const _Float16 l = (_Float16)(a - (float)h);
        h2[q] = __builtin_bit_cast(u16, h);
        l2[q] = __builtin_bit_cast(u16, l);
      }
      hp[e2] = (u32)h2[0] | ((u32)h2[1] << 16);
      lp[e2] = (u32)l2[0] | ((u32)l2[1] << 16);
    }

    char* lh = lds + chl * 2048 + rg * 1024 + row * 16;
    *(uint4*)(lh)        = make_uint4(hp[0], hp[1], hp[2], hp[3]);  // oct0 (k0-7)
    *(uint4*)(lh + 512)  = make_uint4(hp[4], hp[5], hp[6], hp[7]);  // oct1 (k8-15)
    char* llo = lh + 8192;
    *(uint4*)(llo)       = make_uint4(lp[0], lp[1], lp[2], lp[3]);
    *(uint4*)(llo + 512) = make_uint4(lp[4], lp[5], lp[6], lp[7]);
    __syncthreads();

    const size_t gb = (size_t)(mblk * 64 + chg * 4) * 2048;
    const int off = tid * 16;
    *(uint4*)((char*)XH + gb + off)        = *(const uint4*)(lds + off);
    *(uint4*)((char*)XH + gb + off + 4096) = *(const uint4*)(lds + off + 4096);
    *(uint4*)((char*)XL + gb + off)        = *(const uint4*)(lds + 8192 + off);
    *(uint4*)((char*)XL + gb + off + 4096) = *(const uint4*)(lds + 8192 + off + 4096);
  } else {
    // W: lane runs along n -> stores already lane-contiguous.
    const int g = (b - 512) * 256 + tid;
    const int n = g & 1023, ch = g >> 10;
    const int nblk = n >> 6, ng = (n >> 5) & 1, n32 = n & 31;
    const float* wp = w + (size_t)(ch * 16) * N_TOT + n;
    u32 hp[8], lp[8];
#pragma unroll
    for (int e2 = 0; e2 < 8; ++e2) {
      u16 h2[2], l2[2];
#pragma unroll
      for (int q = 0; q < 2; ++q) {
        const int e = e2 * 2 + q;
        const float v = wp[(size_t)e * N_TOT];
        const int wi = (int)(v + 8.0f);
        const float a = (v + wl[e * 16 + wi]) * 0.0625f;  // fold 1/16 into B (exact)
        const _Float16 h = (_Float16)a;
        const _Float16 l = (_Float16)(a - (float)h);
        h2[q] = __builtin_bit_cast(u16, h);
        l2[q] = __builtin_bit_cast(u16, l);
      }
      hp[e2] = (u32)h2[0] | ((u32)h2[1] << 16);
      lp[e2] = (u32)l2[0] | ((u32)l2[1] << 16);
    }
    const size_t base = (size_t)(nblk * 64 + ch) * 1024 + ng * 512 + n32 * 8;
    *(uint4*)&WH[base]       = make_uint4(hp[0], hp[1], hp[2], hp[3]);  // oct0
    *(uint4*)&WH[base + 256] = make_uint4(hp[4], hp[5], hp[6], hp[7]);  // oct1
    *(uint4*)&WL[base]       = make_uint4(lp[0], lp[1], lp[2], lp[3]);
    *(uint4*)&WL[base + 256] = make_uint4(lp[4], lp[5], lp[6], lp[7]);
  }
}

__global__ __launch_bounds__(256, 2) void opu_main(
    const u16* __restrict__ XH, const u16* __restrict__ XL,
    const u16* __restrict__ WH, const u16* __restrict__ WL,
    float* __restrict__ out, size_t rep_stride)
{
  __shared__ float cb[64 * 64];   // 16KB combine buffer

  const int tid  = threadIdx.x;
  const int wave = tid >> 6;      // k-slice: chunks [wave*16, wave*16+16)
  const int lane = tid & 63;
  const int oct  = lane >> 5;
  const int ll   = lane & 31;

  const int bx   = blockIdx.x;
  const int nblk = (bx & 1) + 2 * ((bx >> 3) & 7);   // 0..15
  const int mblk = ((bx >> 1) & 3) + 4 * (bx >> 6);  // 0..31

  const size_t ck0 = (size_t)(wave * 16) * 1024;

#pragma unroll 1
  for (int rep = 0; rep < 3; ++rep) {
    // rep_stride is 0 at runtime; being a runtime value it blocks CSE/elision of reps.
    const size_t rs = (size_t)rep * rep_stride;
    const u16* pAh = XH + rs + (size_t)mblk * 65536 + ck0 + lane * 8;
    const u16* pAl = XL + rs + (size_t)mblk * 65536 + ck0 + lane * 8;
    const u16* pBh = WH + rs + (size_t)nblk * 65536 + ck0 + lane * 8;
    const u16* pBl = WL + rs + (size_t)nblk * 65536 + ck0 + lane * 8;

    uint4 b0[8], b1[8];  // literal-indexed only (R7 lesson: %3 ring -> scratch spill)

#define LOADCH(dst, off)                                  \
  do {                                                    \
    (dst)[0] = *(const uint4*)(pAh + (off));              \
    (dst)[1] = *(const uint4*)(pAh + (off) + 512);        \
    (dst)[2] = *(const uint4*)(pAl + (off));              \
    (dst)[3] = *(const uint4*)(pAl + (off) + 512);        \
    (dst)[4] = *(const uint4*)(pBh + (off));              \
    (dst)[5] = *(const uint4*)(pBh + (off) + 512);        \
    (dst)[6] = *(const uint4*)(pBl + (off));              \
    (dst)[7] = *(const uint4*)(pBl + (off) + 512);        \
  } while (0)

    float res[4][16];
#pragma unroll
    for (int t = 0; t < 4; ++t)
#pragma unroll
      for (int i = 0; i < 16; ++i) res[t][i] = 0.0f;
    const f32x16 fzero = {};

#define COMPUTE(c)                                                                     \
  do {                                                                                 \
    _Pragma("unroll")                                                                  \
    for (int mt = 0; mt < 2; ++mt)                                                     \
      _Pragma("unroll")                                                                \
      for (int nt = 0; nt < 2; ++nt) {                                                 \
        const f16x8 Ah = __builtin_bit_cast(f16x8, (c)[mt]);                           \
        const f16x8 Al = __builtin_bit_cast(f16x8, (c)[2 + mt]);                       \
        const f16x8 Bh = __builtin_bit_cast(f16x8, (c)[4 + nt]);                       \
        const f16x8 Bl = __builtin_bit_cast(f16x8, (c)[6 + nt]);                       \
        f32x16 acc = __builtin_amdgcn_mfma_f32_32x32x16_f16(Ah, Bh, fzero, 0, 0, 0);   \
        acc = __builtin_amdgcn_mfma_f32_32x32x16_f16(Al, Bh, acc, 0, 0, 0);            \
        acc = __builtin_amdgcn_mfma_f32_32x32x16_f16(Ah, Bl, acc, 0, 0, 0);            \
        float* r4 = res[mt * 2 + nt];                                                  \
        _Pragma("unroll")                                                              \
        for (int i = 0; i < 16; ++i)                                                   \
          r4[i] += __builtin_rintf(acc[i]);  /* acc = mm/16; clip provably dead */     \
      }                                                                                \
  } while (0)

    LOADCH(b0, 0);
#pragma unroll 1
    for (int c2 = 0; c2 < 8; ++c2) {
      const size_t o = (size_t)c2 * 2048;          // 2 chunks of 1024 u16
      LOADCH(b1, o + 1024);                        // prefetch odd chunk
      COMPUTE(b0);
      if (c2 < 7) LOADCH(b0, o + 2048);            // prefetch next even chunk
      COMPUTE(b1);
    }

    // ---- combine the 4 waves' k-slices through LDS (integer-valued f32, exact) ----
#define CBIDX(mt, nt, i) ((((mt) * 32) + ((i & 3) + 8 * (i >> 2) + 4 * oct)) * 64 + (nt) * 32 + ll)
    __syncthreads();   // cb safe to overwrite (prev rep's readers done)
    if (wave == 0) {
#pragma unroll
      for (int mt = 0; mt < 2; ++mt)
#pragma unroll
        for (int nt = 0; nt < 2; ++nt)
#pragma unroll
          for (int i = 0; i < 16; ++i) cb[CBIDX(mt, nt, i)] = res[mt * 2 + nt][i];
    }
    __syncthreads();
    if (wave == 1) {
#pragma unroll
      for (int mt = 0; mt < 2; ++mt)
#pragma unroll
        for (int nt = 0; nt < 2; ++nt)
#pragma unroll
          for (int i = 0; i < 16; ++i) cb[CBIDX(mt, nt, i)] += res[mt * 2 + nt][i];
    }
    __syncthreads();
    if (wave == 2) {
#pragma unroll
      for (int mt = 0; mt < 2; ++mt)
#pragma unroll
        for (int nt = 0; nt < 2; ++nt)
#pragma unroll
          for (int i = 0; i < 16; ++i) cb[CBIDX(mt, nt, i)] += res[mt * 2 + nt][i];
    }
    __syncthreads();
    if (wave == 3) {
#pragma unroll
      for (int mt = 0; mt < 2; ++mt)
#pragma unroll
        for (int nt = 0; nt < 2; ++nt)
#pragma unroll
          for (int i = 0; i < 16; ++i) cb[CBIDX(mt, nt, i)] += res[mt * 2 + nt][i];
    }
    __syncthreads();

    // ---- cooperative x16 store (every rep; identical values -> idempotent) ----
    const float4* cbv = (const float4*)cb;
    const int row = tid >> 2, c4 = tid & 3;
    float* orow = out + (size_t)(mblk * 64 + row) * N_TOT + nblk * 64;
#pragma unroll
    for (int p = 0; p < 4; ++p) {
      float4 v = cbv[row * 16 + c4 + 4 * p];
      v.x *= 16.0f; v.y *= 16.0f; v.z *= 16.0f; v.w *= 16.0f;
      *(float4*)&orow[(c4 + 4 * p) * 4] = v;
    }
  }
}

extern "C" void kernel_launch(void* const* d_in, const int* in_sizes, int n_in,
                              void* d_out, int out_size, void* d_ws, size_t ws_size,
                              hipStream_t stream)
{
  const float* input  = (const float*)d_in[0];
  const float* weight = (const float*)d_in[1];
  const float* vmap   = (const float*)d_in[2];
  const float* wmap   = (const float*)d_in[3];
  float* out = (float*)d_out;

  u16* XH = (u16*)d_ws;                          // 4MB (2M u16)
  u16* XL = XH + 2 * 1024 * 1024;                // 4MB
  u16* WH = XL + 2 * 1024 * 1024;                // 2MB
  u16* WL = WH + 1024 * 1024;                    // 2MB   (ws use: 12MB total)

  presplit<<<768, 256, 0, stream>>>(input, weight, vmap, wmap, XH, XL, WH, WL);

  opu_main<<<512, 256, 0, stream>>>(XH, XL, WH, WL, out, (size_t)0);
}

// Round 14
// 90.236 us; speedup vs baseline: 1.3677x; 1.3677x over previous
//
#include <hip/hip_runtime.h>

// OPU via MFMA, R14 = R11 with COMPUTE restructured to break MFMA dependency chains.
// R13 measurement (x3-rep, first direct counters): MfmaUtil 25% / VALUBusy 34% / Occ 17% /
// FETCH 12MB/rep (compulsory only) -> no pipe saturated, effective ~97 cyc/MFMA vs 8 ideal:
// the old COMPUTE ran each quadrant as a 3-deep dependent MFMA chain followed immediately
// by quant VALU reading acc -> program-order serialization (this also explains R8/R9/R12
// neutrality: prefetch/traffic/TLP never touched the intra-wave hazard).
// Fix: keep 4 quadrant accs live; issue MFMAs in rounds (AhBh x4, AlBh x4, AhBl x4 - each
// consecutive MFMA independent, chain distance 32cyc ~ latency), quant afterward (accs aged
// >= 40cyc). Bit-identical per-element math and order -> absmax 16 unchanged.
// Everything else identical to R11 (best known 91.1us):
//   presplit: a = fl(x + vlut[k%16][x+8]); b = fl(w + wlut[k%16][w+8])*(1/16) (exact);
//   f16 hi/lo split; planes XH/XL[mblk32][chunk64][rg2][oct2][row32][k8],
//   WH/WL[nblk16][chunk64][ng2][oct2][n32][k8] u16; LDS-transposed coalesced X stores.
//   main: 512 blocks (2/CU) x 256 thr; block = 64x64 tile; wave = 16-chunk k-slice;
//   literal double-buffer (R7 scratch lesson), AlBl dropped (|err|<=4e-6 of rint grid),
//   res += rndne(acc) (clip provably dead: |mm/16| <= 8.3^2 < 127.5),
//   4-barrier LDS combine, x16 store. Swizzle: per-XCD A 2MB + B 2MB.

typedef unsigned int u32;
typedef unsigned short u16;
typedef _Float16 f16x8 __attribute__((ext_vector_type(8)));
typedef float f32x16 __attribute__((ext_vector_type(16)));

#define M_TOT 2048
#define N_TOT 1024
#define K_TOT 1024

__global__ __launch_bounds__(256) void presplit(
    const float* __restrict__ x, const float* __restrict__ w,
    const float* __restrict__ vl, const float* __restrict__ wl,
    u16* __restrict__ XH, u16* __restrict__ XL,
    u16* __restrict__ WH, u16* __restrict__ WL)
{
  __shared__ __align__(16) char lds[16384];   // [H 8KB | L 8KB], 4 chunk-planes each
  const int b = blockIdx.x;
  const int tid = threadIdx.x;

  if (b < 512) {
    // X: block = (mblk, chunk-group of 4). thread = (m_local, ch_local).
    const int mblk = b >> 4, chg = b & 15;
    const int ml = tid >> 2, chl = tid & 3;
    const int rg = ml >> 5, row = ml & 31;
    const int m = mblk * 64 + ml;
    const float* xp = x + (size_t)m * K_TOT + (chg * 4 + chl) * 16;

    u32 hp[8], lp[8];
#pragma unroll
    for (int e2 = 0; e2 < 8; ++e2) {
      u16 h2[2], l2[2];
#pragma unroll
      for (int q = 0; q < 2; ++q) {
        const int e = e2 * 2 + q;
        const float v = xp[e];
        const int xi = (int)(v + 8.0f);          // x always in [-8,7]
        const float a = v + vl[e * 16 + xi];     // j = k%16 = e (chunk-aligned)
        const _Float16 h = (_Float16)a;
        const _Float16 l = (_Float16)(a - (float)h);
        h2[q] = __builtin_bit_cast(u16, h);
        l2[q] = __builtin_bit_cast(u16, l);
      }
      hp[e2] = (u32)h2[0] | ((u32)h2[1] << 16);
      lp[e2] = (u32)l2[0] | ((u32)l2[1] << 16);
    }

    char* lh = lds + chl * 2048 + rg * 1024 + row * 16;
    *(uint4*)(lh)        = make_uint4(hp[0], hp[1], hp[2], hp[3]);  // oct0 (k0-7)
    *(uint4*)(lh + 512)  = make_uint4(hp[4], hp[5], hp[6], hp[7]);  // oct1 (k8-15)
    char* llo = lh + 8192;
    *(uint4*)(llo)       = make_uint4(lp[0], lp[1], lp[2], lp[3]);
    *(uint4*)(llo + 512) = make_uint4(lp[4], lp[5], lp[6], lp[7]);
    __syncthreads();

    const size_t gb = (size_t)(mblk * 64 + chg * 4) * 2048;
    const int off = tid * 16;
    *(uint4*)((char*)XH + gb + off)        = *(const uint4*)(lds + off);
    *(uint4*)((char*)XH + gb + off + 4096) = *(const uint4*)(lds + off + 4096);
    *(uint4*)((char*)XL + gb + off)        = *(const uint4*)(lds + 8192 + off);
    *(uint4*)((char*)XL + gb + off + 4096) = *(const uint4*)(lds + 8192 + off + 4096);
  } else {
    // W: lane runs along n -> stores already lane-contiguous.
    const int g = (b - 512) * 256 + tid;
    const int n = g & 1023, ch = g >> 10;
    const int nblk = n >> 6, ng = (n >> 5) & 1, n32 = n & 31;
    const float* wp = w + (size_t)(ch * 16) * N_TOT + n;
    u32 hp[8], lp[8];
#pragma unroll
    for (int e2 = 0; e2 < 8; ++e2) {
      u16 h2[2], l2[2];
#pragma unroll
      for (int q = 0; q < 2; ++q) {
        const int e = e2 * 2 + q;
        const float v = wp[(size_t)e * N_TOT];
        const int wi = (int)(v + 8.0f);
        const float a = (v + wl[e * 16 + wi]) * 0.0625f;  // fold 1/16 into B (exact)
        const _Float16 h = (_Float16)a;
        const _Float16 l = (_Float16)(a - (float)h);
        h2[q] = __builtin_bit_cast(u16, h);
        l2[q] = __builtin_bit_cast(u16, l);
      }
      hp[e2] = (u32)h2[0] | ((u32)h2[1] << 16);
      lp[e2] = (u32)l2[0] | ((u32)l2[1] << 16);
    }
    const size_t base = (size_t)(nblk * 64 + ch) * 1024 + ng * 512 + n32 * 8;
    *(uint4*)&WH[base]       = make_uint4(hp[0], hp[1], hp[2], hp[3]);  // oct0
    *(uint4*)&WH[base + 256] = make_uint4(hp[4], hp[5], hp[6], hp[7]);  // oct1
    *(uint4*)&WL[base]       = make_uint4(lp[0], lp[1], lp[2], lp[3]);
    *(uint4*)&WL[base + 256] = make_uint4(lp[4], lp[5], lp[6], lp[7]);
  }
}

__global__ __launch_bounds__(256, 2) void opu_main(
    const u16* __restrict__ XH, const u16* __restrict__ XL,
    const u16* __restrict__ WH, const u16* __restrict__ WL,
    float* __restrict__ out)
{
  __shared__ float cb[64 * 64];   // 16KB combine buffer

  const int tid  = threadIdx.x;
  const int wave = tid >> 6;      // k-slice: chunks [wave*16, wave*16+16)
  const int lane = tid & 63;
  const int oct  = lane >> 5;
  const int ll   = lane & 31;

  const int bx   = blockIdx.x;
  const int nblk = (bx & 1) + 2 * ((bx >> 3) & 7);   // 0..15
  const int mblk = ((bx >> 1) & 3) + 4 * (bx >> 6);  // 0..31

  const size_t ck0 = (size_t)(wave * 16) * 1024;
  const u16* pAh = XH + (size_t)mblk * 65536 + ck0 + lane * 8;
  const u16* pAl = XL + (size_t)mblk * 65536 + ck0 + lane * 8;
  const u16* pBh = WH + (size_t)nblk * 65536 + ck0 + lane * 8;
  const u16* pBl = WL + (size_t)nblk * 65536 + ck0 + lane * 8;

  uint4 b0[8], b1[8];  // literal-indexed only (R7 lesson: %3 ring -> scratch spill)

#define LOADCH(dst, off)                                  \
  do {                                                    \
    (dst)[0] = *(const uint4*)(pAh + (off));              \
    (dst)[1] = *(const uint4*)(pAh + (off) + 512);        \
    (dst)[2] = *(const uint4*)(pAl + (off));              \
    (dst)[3] = *(const uint4*)(pAl + (off) + 512);        \
    (dst)[4] = *(const uint4*)(pBh + (off));              \
    (dst)[5] = *(const uint4*)(pBh + (off) + 512);        \
    (dst)[6] = *(const uint4*)(pBl + (off));              \
    (dst)[7] = *(const uint4*)(pBl + (off) + 512);        \
  } while (0)

  float res[4][16];
#pragma unroll
  for (int t = 0; t < 4; ++t)
#pragma unroll
    for (int i = 0; i < 16; ++i) res[t][i] = 0.0f;
  const f32x16 fzero = {};

  // Round-interleaved: consecutive MFMAs independent (4 live accs); quant only after
  // all 12 issued -> accs aged past MFMA latency. Same per-element math/order as R11.
#define COMPUTE(c)                                                                     \
  do {                                                                                 \
    const f16x8 Ah0 = __builtin_bit_cast(f16x8, (c)[0]);                               \
    const f16x8 Ah1 = __builtin_bit_cast(f16x8, (c)[1]);                               \
    const f16x8 Al0 = __builtin_bit_cast(f16x8, (c)[2]);                               \
    const f16x8 Al1 = __builtin_bit_cast(f16x8, (c)[3]);                               \
    const f16x8 Bh0 = __builtin_bit_cast(f16x8, (c)[4]);                               \
    const f16x8 Bh1 = __builtin_bit_cast(f16x8, (c)[5]);                               \
    const f16x8 Bl0 = __builtin_bit_cast(f16x8, (c)[6]);                               \
    const f16x8 Bl1 = __builtin_bit_cast(f16x8, (c)[7]);                               \
    f32x16 a0 = __builtin_amdgcn_mfma_f32_32x32x16_f16(Ah0, Bh0, fzero, 0, 0, 0);      \
    f32x16 a1 = __builtin_amdgcn_mfma_f32_32x32x16_f16(Ah0, Bh1, fzero, 0, 0, 0);      \
    f32x16 a2 = __builtin_amdgcn_mfma_f32_32x32x16_f16(Ah1, Bh0, fzero, 0, 0, 0);      \
    f32x16 a3 = __builtin_amdgcn_mfma_f32_32x32x16_f16(Ah1, Bh1, fzero, 0, 0, 0);      \
    a0 = __builtin_amdgcn_mfma_f32_32x32x16_f16(Al0, Bh0, a0, 0, 0, 0);                \
    a1 = __builtin_amdgcn_mfma_f32_32x32x16_f16(Al0, Bh1, a1, 0, 0, 0);                \
    a2 = __builtin_amdgcn_mfma_f32_32x32x16_f16(Al1, Bh0, a2, 0, 0, 0);                \
    a3 = __builtin_amdgcn_mfma_f32_32x32x16_f16(Al1, Bh1, a3, 0, 0, 0);                \
    a0 = __builtin_amdgcn_mfma_f32_32x32x16_f16(Ah0, Bl0, a0, 0, 0, 0);                \
    a1 = __builtin_amdgcn_mfma_f32_32x32x16_f16(Ah0, Bl1, a1, 0, 0, 0);                \
    a2 = __builtin_amdgcn_mfma_f32_32x32x16_f16(Ah1, Bl0, a2, 0, 0, 0);                \
    a3 = __builtin_amdgcn_mfma_f32_32x32x16_f16(Ah1, Bl1, a3, 0, 0, 0);                \
    _Pragma("unroll")                                                                  \
    for (int i = 0; i < 16; ++i) res[0][i] += __builtin_rintf(a0[i]);                  \
    _Pragma("unroll")                                                                  \
    for (int i = 0; i < 16; ++i) res[1][i] += __builtin_rintf(a1[i]);                  \
    _Pragma("unroll")                                                                  \
    for (int i = 0; i < 16; ++i) res[2][i] += __builtin_rintf(a2[i]);                  \
    _Pragma("unroll")                                                                  \
    for (int i = 0; i < 16; ++i) res[3][i] += __builtin_rintf(a3[i]);                  \
  } while (0)

  LOADCH(b0, 0);
#pragma unroll 1
  for (int c2 = 0; c2 < 8; ++c2) {
    const size_t o = (size_t)c2 * 2048;          // 2 chunks of 1024 u16
    LOADCH(b1, o + 1024);                        // prefetch odd chunk
    COMPUTE(b0);
    if (c2 < 7) LOADCH(b0, o + 2048);            // prefetch next even chunk
    COMPUTE(b1);
  }

  // ---- combine the 4 waves' k-slices through LDS (integer-valued f32, exact) ----
#define CBIDX(mt, nt, i) ((((mt) * 32) + ((i & 3) + 8 * (i >> 2) + 4 * oct)) * 64 + (nt) * 32 + ll)
  if (wave == 0) {
#pragma unroll
    for (int mt = 0; mt < 2; ++mt)
#pragma unroll
      for (int nt = 0; nt < 2; ++nt)
#pragma unroll
        for (int i = 0; i < 16; ++i) cb[CBIDX(mt, nt, i)] = res[mt * 2 + nt][i];
  }
  __syncthreads();
  if (wave == 1) {
#pragma unroll
    for (int mt = 0; mt < 2; ++mt)
#pragma unroll
      for (int nt = 0; nt < 2; ++nt)
#pragma unroll
        for (int i = 0; i < 16; ++i) cb[CBIDX(mt, nt, i)] += res[mt * 2 + nt][i];
  }
  __syncthreads();
  if (wave == 2) {
#pragma unroll
    for (int mt = 0; mt < 2; ++mt)
#pragma unroll
      for (int nt = 0; nt < 2; ++nt)
#pragma unroll
        for (int i = 0; i < 16; ++i) cb[CBIDX(mt, nt, i)] += res[mt * 2 + nt][i];
  }
  __syncthreads();
  if (wave == 3) {
#pragma unroll
    for (int mt = 0; mt < 2; ++mt)
#pragma unroll
      for (int nt = 0; nt < 2; ++nt)
#pragma unroll
        for (int i = 0; i < 16; ++i) cb[CBIDX(mt, nt, i)] += res[mt * 2 + nt][i];
  }
  __syncthreads();

  // ---- cooperative x16 store ----
  const float4* cbv = (const float4*)cb;
  const int row = tid >> 2, c4 = tid & 3;
  float* orow = out + (size_t)(mblk * 64 + row) * N_TOT + nblk * 64;
#pragma unroll
  for (int p = 0; p < 4; ++p) {
    float4 v = cbv[row * 16 + c4 + 4 * p];
    v.x *= 16.0f; v.y *= 16.0f; v.z *= 16.0f; v.w *= 16.0f;
    *(float4*)&orow[(c4 + 4 * p) * 4] = v;
  }
}

extern "C" void kernel_launch(void* const* d_in, const int* in_sizes, int n_in,
                              void* d_out, int out_size, void* d_ws, size_t ws_size,
                              hipStream_t stream)
{
  const float* input  = (const float*)d_in[0];
  const float* weight = (const float*)d_in[1];
  const float* vmap   = (const float*)d_in[2];
  const float* wmap   = (const float*)d_in[3];
  float* out = (float*)d_out;

  u16* XH = (u16*)d_ws;                          // 4MB (2M u16)
  u16* XL = XH + 2 * 1024 * 1024;                // 4MB
  u16* WH = XL + 2 * 1024 * 1024;                // 2MB
  u16* WL = WH + 1024 * 1024;                    // 2MB   (ws use: 12MB total)

  presplit<<<768, 256, 0, stream>>>(input, weight, vmap, wmap, XH, XL, WH, WL);

  opu_main<<<512, 256, 0, stream>>>(XH, XL, WH, WL, out);
}

// Round 15
// 88.137 us; speedup vs baseline: 1.4002x; 1.0238x over previous
//
#include <hip/hip_runtime.h>

// OPU via MFMA, R15 = R14 main (merged-plane layout) + table-driven presplit.
// R14 lesson: MFMA chain interleave neutral (compiler already scheduled it); R13 counters
// recalibrated: MfmaUtil 25% = pipe-OCCUPANCY (~32cyc/MFMA), issue only ~6% -> MFMA never
// the binder. VALUBusy ~7us/rep explained by VGPR_Count 112: res/acc in AGPRs -> accvgpr
// copy traffic per quant element. Ledger: C+presplit ~= 62-66us, C ~= 50 -> presplit
// ~12-16us, as big as main, never optimized.
// R15: a = fl(x + vlut[j][xi]) takes only 256 values (j,xi) -> build packed hi/lo u32
// table in LDS per block (bit-identical fp32 math), element loop = index + LDS gather +
// pk-pack (~5 VALU/elem vs ~12, no global gathers, no f16-cvt chains).
// Merged planes (hi/lo adjacent per chunk -> one 4KB page per chunk, 1 base reg/matrix):
//   XHL[mblk32][chunk64][hl2][rg2][oct2][row32][k8] u16   (4KB per (mblk,chunk))
//   WHL[nblk16][chunk64][hl2][ng2][oct2][n32][k8]  u16
// main: unchanged structure (512 blocks, 2/CU, 256 thr; block = 64x64 tile; wave =
// 16-chunk k-slice; literal double-buffer; round-interleaved 12 MFMA/chunk, AlBl dropped
// (|err|<=4e-6 of rint grid); res += rndne(acc), clip provably dead (|mm/16|<=68.9<127.5);
// 4-barrier LDS combine; x16 store). Swizzle: per-XCD A 2MB + B 2MB.

typedef unsigned int u32;
typedef unsigned short u16;
typedef _Float16 f16x8 __attribute__((ext_vector_type(8)));
typedef float f32x16 __attribute__((ext_vector_type(16)));

#define M_TOT 2048
#define N_TOT 1024
#define K_TOT 1024

__device__ __forceinline__ u32 split_pack(float a) {
  _Float16 h = (_Float16)a;              // v_cvt_f16_f32 (RNE)
  _Float16 l = (_Float16)(a - (float)h); // exact fp32 sub then RNE
  return (u32)__builtin_bit_cast(u16, h) | ((u32)__builtin_bit_cast(u16, l) << 16);
}
__device__ __forceinline__ u32 pk_lo(u32 a, u32 b) { return (a & 0xffffu) | (b << 16); }
__device__ __forceinline__ u32 pk_hi(u32 a, u32 b) { return (a >> 16) | (b & 0xffff0000u); }

__global__ __launch_bounds__(256) void presplit(
    const float* __restrict__ x, const float* __restrict__ w,
    const float* __restrict__ vl, const float* __restrict__ wl,
    u16* __restrict__ XHL, u16* __restrict__ WHL)
{
  __shared__ __align__(16) char lds[16384];  // X: 4-chunk plane image; W: unused
  __shared__ u32 tab[256];                   // packed hi/lo split table
  const int b = blockIdx.x;
  const int tid = threadIdx.x;

  if (b < 512) {
    // ---- X: block = (mblk, chunk-group of 4); thread = (m_local, ch_local) ----
    // table: a = fl((xi-8) + vl[j][xi]) - bit-identical to per-element path
    {
      const int j = tid >> 4, xi = tid & 15;
      tab[tid] = split_pack((float)(xi - 8) + vl[j * 16 + xi]);
    }
    __syncthreads();

    const int mblk = b >> 4, chg = b & 15;
    const int ml = tid >> 2, chl = tid & 3;
    const int rg = ml >> 5, row = ml & 31;
    const float4* xp4 = (const float4*)(x + (size_t)(mblk * 64 + ml) * K_TOT + (chg * 4 + chl) * 16);
    float4 v4[4] = { xp4[0], xp4[1], xp4[2], xp4[3] };
    const float* v = (const float*)v4;

    u32 hp[8], lp[8];
#pragma unroll
    for (int e2 = 0; e2 < 8; ++e2) {
      const int e = e2 * 2;
      const u32 t0 = tab[e * 16 + (int)(v[e] + 8.0f)];
      const u32 t1 = tab[(e + 1) * 16 + (int)(v[e + 1] + 8.0f)];
      hp[e2] = pk_lo(t0, t1);
      lp[e2] = pk_hi(t0, t1);
    }

    // LDS image in exact global layout: chl*4096 + hl*2048 + rg*1024 + oct*512 + row*16 (bytes)
    char* base = lds + chl * 4096 + rg * 1024 + row * 16;
    *(uint4*)(base)        = make_uint4(hp[0], hp[1], hp[2], hp[3]);  // h oct0
    *(uint4*)(base + 512)  = make_uint4(hp[4], hp[5], hp[6], hp[7]);  // h oct1
    *(uint4*)(base + 2048) = make_uint4(lp[0], lp[1], lp[2], lp[3]);  // l oct0
    *(uint4*)(base + 2560) = make_uint4(lp[4], lp[5], lp[6], lp[7]);  // l oct1
    __syncthreads();

    // coalesced dump: 16KB contiguous (4 chunk-planes)
    const size_t gb = (size_t)(mblk * 64 + chg * 4) * 4096;  // bytes
    const int off = tid * 16;
    *(uint4*)((char*)XHL + gb + off)         = *(const uint4*)(lds + off);
    *(uint4*)((char*)XHL + gb + off + 4096)  = *(const uint4*)(lds + off + 4096);
    *(uint4*)((char*)XHL + gb + off + 8192)  = *(const uint4*)(lds + off + 8192);
    *(uint4*)((char*)XHL + gb + off + 12288) = *(const uint4*)(lds + off + 12288);
  } else {
    // ---- W: thread = (n, chunk); stores already lane-contiguous ----
    {
      const int j = tid >> 4, wi = tid & 15;
      // b = fl(fl((wi-8) + wl[j][wi]) * (1/16)) - exact pow2 fold, bit-identical
      tab[tid] = split_pack(((float)(wi - 8) + wl[j * 16 + wi]) * 0.0625f);
    }
    __syncthreads();

    const int g = (b - 512) * 256 + tid;          // over 64 ch x 1024 n
    const int n = g & 1023, ch = g >> 10;
    const int nblk = n >> 6, ng = (n >> 5) & 1, n32 = n & 31;
    const float* wp = w + (size_t)(ch * 16) * N_TOT + n;

    u32 hp[8], lp[8];
#pragma unroll
    for (int e2 = 0; e2 < 8; ++e2) {
      const int e = e2 * 2;
      const float w0 = wp[(size_t)e * N_TOT];
      const float w1 = wp[(size_t)(e + 1) * N_TOT];
      const u32 t0 = tab[e * 16 + (int)(w0 + 8.0f)];
      const u32 t1 = tab[(e + 1) * 16 + (int)(w1 + 8.0f)];
      hp[e2] = pk_lo(t0, t1);
      lp[e2] = pk_hi(t0, t1);
    }
    // chunk base (u16): (nblk*64+ch)*2048; layout hl*1024 + ng*512 + oct*256 + n32*8
    const size_t base = (size_t)(nblk * 64 + ch) * 2048 + ng * 512 + n32 * 8;
    *(uint4*)&WHL[base]        = make_uint4(hp[0], hp[1], hp[2], hp[3]);  // h oct0
    *(uint4*)&WHL[base + 256]  = make_uint4(hp[4], hp[5], hp[6], hp[7]);  // h oct1
    *(uint4*)&WHL[base + 1024] = make_uint4(lp[0], lp[1], lp[2], lp[3]);  // l oct0
    *(uint4*)&WHL[base + 1280] = make_uint4(lp[4], lp[5], lp[6], lp[7]);  // l oct1
  }
}

__global__ __launch_bounds__(256, 2) void opu_main(
    const u16* __restrict__ XHL, const u16* __restrict__ WHL,
    float* __restrict__ out)
{
  __shared__ float cb[64 * 64];   // 16KB combine buffer

  const int tid  = threadIdx.x;
  const int wave = tid >> 6;      // k-slice: chunks [wave*16, wave*16+16)
  const int lane = tid & 63;
  const int oct  = lane >> 5;
  const int ll   = lane & 31;

  const int bx   = blockIdx.x;
  const int nblk = (bx & 1) + 2 * ((bx >> 3) & 7);   // 0..15
  const int mblk = ((bx >> 1) & 3) + 4 * (bx >> 6);  // 0..31

  // chunk stride 2048 u16 (4KB page: [hl][rg|ng][oct][32][k8])
  const u16* pA = XHL + (size_t)mblk * 131072 + (size_t)(wave * 16) * 2048 + lane * 8;
  const u16* pB = WHL + (size_t)nblk * 131072 + (size_t)(wave * 16) * 2048 + lane * 8;

  uint4 b0[8], b1[8];  // literal-indexed only (R7 lesson: %3 ring -> scratch spill)

#define LOADCH(dst, off)                                  \
  do {                                                    \
    (dst)[0] = *(const uint4*)(pA + (off));               \
    (dst)[1] = *(const uint4*)(pA + (off) + 512);         \
    (dst)[2] = *(const uint4*)(pA + (off) + 1024);        \
    (dst)[3] = *(const uint4*)(pA + (off) + 1536);        \
    (dst)[4] = *(const uint4*)(pB + (off));               \
    (dst)[5] = *(const uint4*)(pB + (off) + 512);         \
    (dst)[6] = *(const uint4*)(pB + (off) + 1024);        \
    (dst)[7] = *(const uint4*)(pB + (off) + 1536);        \
  } while (0)

  float res[4][16];
#pragma unroll
  for (int t = 0; t < 4; ++t)
#pragma unroll
    for (int i = 0; i < 16; ++i) res[t][i] = 0.0f;
  const f32x16 fzero = {};

  // Round-interleaved (R14): 4 live accs, quant after all 12 issued.
#define COMPUTE(c)                                                                     \
  do {                                                                                 \
    const f16x8 Ah0 = __builtin_bit_cast(f16x8, (c)[0]);                               \
    const f16x8 Ah1 = __builtin_bit_cast(f16x8, (c)[1]);                               \
    const f16x8 Al0 = __builtin_bit_cast(f16x8, (c)[2]);                               \
    const f16x8 Al1 = __builtin_bit_cast(f16x8, (c)[3]);                               \
    const f16x8 Bh0 = __builtin_bit_cast(f16x8, (c)[4]);                               \
    const f16x8 Bh1 = __builtin_bit_cast(f16x8, (c)[5]);                               \
    const f16x8 Bl0 = __builtin_bit_cast(f16x8, (c)[6]);                               \
    const f16x8 Bl1 = __builtin_bit_cast(f16x8, (c)[7]);                               \
    f32x16 a0 = __builtin_amdgcn_mfma_f32_32x32x16_f16(Ah0, Bh0, fzero, 0, 0, 0);      \
    f32x16 a1 = __builtin_amdgcn_mfma_f32_32x32x16_f16(Ah0, Bh1, fzero, 0, 0, 0);      \
    f32x16 a2 = __builtin_amdgcn_mfma_f32_32x32x16_f16(Ah1, Bh0, fzero, 0, 0, 0);      \
    f32x16 a3 = __builtin_amdgcn_mfma_f32_32x32x16_f16(Ah1, Bh1, fzero, 0, 0, 0);      \
    a0 = __builtin_amdgcn_mfma_f32_32x32x16_f16(Al0, Bh0, a0, 0, 0, 0);                \
    a1 = __builtin_amdgcn_mfma_f32_32x32x16_f16(Al0, Bh1, a1, 0, 0, 0);                \
    a2 = __builtin_amdgcn_mfma_f32_32x32x16_f16(Al1, Bh0, a2, 0, 0, 0);                \
    a3 = __builtin_amdgcn_mfma_f32_32x32x16_f16(Al1, Bh1, a3, 0, 0, 0);                \
    a0 = __builtin_amdgcn_mfma_f32_32x32x16_f16(Ah0, Bl0, a0, 0, 0, 0);                \
    a1 = __builtin_amdgcn_mfma_f32_32x32x16_f16(Ah0, Bl1, a1, 0, 0, 0);                \
    a2 = __builtin_amdgcn_mfma_f32_32x32x16_f16(Ah1, Bl0, a2, 0, 0, 0);                \
    a3 = __builtin_amdgcn_mfma_f32_32x32x16_f16(Ah1, Bl1, a3, 0, 0, 0);                \
    _Pragma("unroll")                                                                  \
    for (int i = 0; i < 16; ++i) res[0][i] += __builtin_rintf(a0[i]);                  \
    _Pragma("unroll")                                                                  \
    for (int i = 0; i < 16; ++i) res[1][i] += __builtin_rintf(a1[i]);                  \
    _Pragma("unroll")                                                                  \
    for (int i = 0; i < 16; ++i) res[2][i] += __builtin_rintf(a2[i]);                  \
    _Pragma("unroll")                                                                  \
    for (int i = 0; i < 16; ++i) res[3][i] += __builtin_rintf(a3[i]);                  \
  } while (0)

  LOADCH(b0, 0);
#pragma unroll 1
  for (int c2 = 0; c2 < 8; ++c2) {
    const size_t o = (size_t)c2 * 4096;          // 2 chunks of 2048 u16
    LOADCH(b1, o + 2048);                        // prefetch odd chunk
    COMPUTE(b0);
    if (c2 < 7) LOADCH(b0, o + 4096);            // prefetch next even chunk
    COMPUTE(b1);
  }

  // ---- combine the 4 waves' k-slices through LDS (integer-valued f32, exact) ----
#define CBIDX(mt, nt, i) ((((mt) * 32) + ((i & 3) + 8 * (i >> 2) + 4 * oct)) * 64 + (nt) * 32 + ll)
  if (wave == 0) {
#pragma unroll
    for (int mt = 0; mt < 2; ++mt)
#pragma unroll
      for (int nt = 0; nt < 2; ++nt)
#pragma unroll
        for (int i = 0; i < 16; ++i) cb[CBIDX(mt, nt, i)] = res[mt * 2 + nt][i];
  }
  __syncthreads();
  if (wave == 1) {
#pragma unroll
    for (int mt = 0; mt < 2; ++mt)
#pragma unroll
      for (int nt = 0; nt < 2; ++nt)
#pragma unroll
        for (int i = 0; i < 16; ++i) cb[CBIDX(mt, nt, i)] += res[mt * 2 + nt][i];
  }
  __syncthreads();
  if (wave == 2) {
#pragma unroll
    for (int mt = 0; mt < 2; ++mt)
#pragma unroll
      for (int nt = 0; nt < 2; ++nt)
#pragma unroll
        for (int i = 0; i < 16; ++i) cb[CBIDX(mt, nt, i)] += res[mt * 2 + nt][i];
  }
  __syncthreads();
  if (wave == 3) {
#pragma unroll
    for (int mt = 0; mt < 2; ++mt)
#pragma unroll
      for (int nt = 0; nt < 2; ++nt)
#pragma unroll
        for (int i = 0; i < 16; ++i) cb[CBIDX(mt, nt, i)] += res[mt * 2 + nt][i];
  }
  __syncthreads();

  // ---- cooperative x16 store ----
  const float4* cbv = (const float4*)cb;
  const int row = tid >> 2, c4 = tid & 3;
  float* orow = out + (size_t)(mblk * 64 + row) * N_TOT + nblk * 64;
#pragma unroll
  for (int p = 0; p < 4; ++p) {
    float4 v = cbv[row * 16 + c4 + 4 * p];
    v.x *= 16.0f; v.y *= 16.0f; v.z *= 16.0f; v.w *= 16.0f;
    *(float4*)&orow[(c4 + 4 * p) * 4] = v;
  }
}

extern "C" void kernel_launch(void* const* d_in, const int* in_sizes, int n_in,
                              void* d_out, int out_size, void* d_ws, size_t ws_size,
                              hipStream_t stream)
{
  const float* input  = (const float*)d_in[0];
  const float* weight = (const float*)d_in[1];
  const float* vmap   = (const float*)d_in[2];
  const float* wmap   = (const float*)d_in[3];
  float* out = (float*)d_out;

  u16* XHL = (u16*)d_ws;                         // 8MB (4M u16)
  u16* WHL = XHL + 4 * 1024 * 1024;              // 4MB   (ws use: 12MB total)

  presplit<<<768, 256, 0, stream>>>(input, weight, vmap, wmap, XHL, WHL);

  opu_main<<<512, 256, 0, stream>>>(XHL, WHL, out);
}